// Round 11
// baseline (391.630 us; speedup 1.0000x reference)
//
#include <hip/hip_runtime.h>

// PDA_GNN: 3-branch LightGCN, bf16 feature storage (f32 arithmetic).
// Round A gathers from ONE shared bf16 init buffer with per-edge bf16-dinv
// dot2 selectors (halves compulsory L2-miss fetch); rounds B/C run weight=1
// on SQ-chained outputs. Padded-bucket CSR build (in-place), MFMA fused tail.
// N=100000, E=1250000, D=64.

constexpr int NN = 100000;
constexpr int NE = 1250000;
constexpr int BROWS = 128;                       // dst nodes per bucket
constexpr int NB = (NN + BROWS - 1) / BROWS;     // 782 buckets
constexpr int PADB = 2048;                       // per-bucket capacity (max ~1780)
constexpr int PADE = NB * PADB;                  // padded edges per set
constexpr int CHUNK = 8192;                      // edges per partition block
constexpr int NCHUNK = (NE + CHUNK - 1) / CHUNK; // 153
constexpr int XROW = 200;                        // bf16 per Xn row (192+8 pad)

typedef short bf16x8 __attribute__((ext_vector_type(8)));
typedef float f32x4 __attribute__((ext_vector_type(4)));

__device__ inline short f2bf(float f) {          // f32 -> bf16 RNE
    unsigned u = __builtin_bit_cast(unsigned, f);
    u += 0x7FFFu + ((u >> 16) & 1u);
    return (short)(u >> 16);
}
__device__ inline unsigned packbf(float a, float b) {
    return (unsigned)(unsigned short)f2bf(a) | ((unsigned)(unsigned short)f2bf(b) << 16);
}
__device__ inline float bflo(unsigned q) { return __builtin_bit_cast(float, q << 16); }
__device__ inline float bfhi(unsigned q) { return __builtin_bit_cast(float, q & 0xFFFF0000u); }

// v_dot2_f32_bf16: D = lo(a)*lo(b) + hi(a)*hi(b) + c   (f32 accumulate)
__device__ inline float dot2bf(unsigned a, unsigned b, float c) {
    float d;
    asm("v_dot2_f32_bf16 %0, %1, %2, %3" : "=v"(d) : "v"(a), "v"(b), "v"(c));
    return d;
}
constexpr unsigned SEL_LO = 0x00003F80u;   // bf16 pair (1.0, 0.0)
constexpr unsigned SEL_HI = 0x3F800000u;   // bf16 pair (0.0, 1.0)

__device__ inline void dotacc(float* acc, uint4 v, unsigned sl, unsigned sh) {
    acc[0] = dot2bf(v.x, sl, acc[0]); acc[1] = dot2bf(v.x, sh, acc[1]);
    acc[2] = dot2bf(v.y, sl, acc[2]); acc[3] = dot2bf(v.y, sh, acc[3]);
    acc[4] = dot2bf(v.z, sl, acc[4]); acc[5] = dot2bf(v.z, sh, acc[5]);
    acc[6] = dot2bf(v.w, sl, acc[6]); acc[7] = dot2bf(v.w, sh, acc[7]);
}

// ---------------------------------------------------------------------------
// init_feat f32 -> bf16 rows (shared round-A source)
// ---------------------------------------------------------------------------
__global__ __launch_bounds__(256) void k_tobf(const float* __restrict__ x, unsigned short* __restrict__ o) {
    int i = blockIdx.x * 256 + threadIdx.x;      // one float4 per thread
    if (i < NN * 16) {
        float4 v = ((const float4*)x)[i];
        uint2 r;
        r.x = packbf(v.x, v.y);
        r.y = packbf(v.z, v.w);
        ((uint2*)o)[i] = r;
    }
}

// W1 [192][128] f32 -> W1t [128][192] bf16
__global__ __launch_bounds__(256) void k_prep(const float* __restrict__ W1, short* __restrict__ W1t) {
    int idx = blockIdx.x * 256 + threadIdx.x;
    if (idx < 128 * 192) {
        int n = idx & 127, k = idx >> 7;
        W1t[n * 192 + k] = f2bf(W1[k * 128 + n]);
    }
}

// gcur[s*NB+b] = b*PADB  (padded bucket bases)
__global__ __launch_bounds__(256) void k_ginit(int* __restrict__ gcur) {
    int i = blockIdx.x * 256 + threadIdx.x;
    if (i < 3 * NB) gcur[i] = (i % NB) * PADB;
}

// ---------------------------------------------------------------------------
// Bucket multisplit into padded regions: LDS-stage 8192 edges, LDS histogram,
// one global atomic per (chunk,bucket), write packed (dlow<<17 | src).
// ---------------------------------------------------------------------------
__global__ __launch_bounds__(256) void k_bscat(const int* __restrict__ e0, const int* __restrict__ e1,
                                               const int* __restrict__ e2,
                                               int* __restrict__ gcur, int* __restrict__ gpacked) {
    __shared__ int lpack[CHUNK];
    __shared__ unsigned short lbkt[CHUNK];
    __shared__ int hist[NB];
    __shared__ int lbase[NB];
    __shared__ int lcur[NB];
    const int tid = threadIdx.x;
    const int set = blockIdx.x / NCHUNK;
    const int chunk = blockIdx.x % NCHUNK;
    const int* ei = (set == 0) ? e0 : (set == 1) ? e1 : e2;
    const int ebase = chunk * CHUNK;

    for (int b = tid; b < NB; b += 256) { hist[b] = 0; lcur[b] = 0; }
    __syncthreads();

    #pragma unroll
    for (int j = 0; j < CHUNK / 256; ++j) {
        int k = tid + j * 256;
        int e = ebase + k;
        if (e < NE) {
            int s = ei[e];
            int d = ei[NE + e];
            int b = d >> 7;
            lpack[k] = ((d & 127) << 17) | s;
            lbkt[k] = (unsigned short)b;
            atomicAdd(&hist[b], 1);
        } else {
            lbkt[k] = 0xFFFFu;
        }
    }
    __syncthreads();
    for (int b = tid; b < NB; b += 256) {
        int h = hist[b];
        if (h > 0) lbase[b] = atomicAdd(&gcur[set * NB + b], h);
    }
    __syncthreads();
    int* gp = gpacked + (size_t)set * PADE;
    #pragma unroll
    for (int j = 0; j < CHUNK / 256; ++j) {
        int k = tid + j * 256;
        unsigned short b = lbkt[k];
        if (b != 0xFFFFu) {
            int pos = lbase[b] + atomicAdd(&lcur[b], 1);
            gp[pos] = lpack[k];
        }
    }
}

// ---------------------------------------------------------------------------
// Per-bucket finalize: stage window in LDS -> per-node cnt/dinv/dsel/rowstart
// (coalesced) + in-place rewrite of the window as per-row CSR (src only).
// dsel[node] = {(bf16(dinv),0),(0,bf16(dinv))} packed dot2 selectors.
// ---------------------------------------------------------------------------
__global__ __launch_bounds__(256) void k_bfin(int* __restrict__ gpacked, const int* __restrict__ gcur,
                                              int* __restrict__ cnt, float* __restrict__ dinv,
                                              uint2* __restrict__ dsel, int* __restrict__ rowstart) {
    __shared__ int win[PADB];
    __shared__ int hist[BROWS];
    __shared__ int rst[BROWS];    // prefix within bucket (relative)
    __shared__ int lcur[BROWS];
    const int tid = threadIdx.x;
    const int set = blockIdx.x / NB, b = blockIdx.x % NB;
    if (tid < BROWS) { hist[tid] = 0; lcur[tid] = 0; }
    __syncthreads();

    const int base = b * PADB;
    const int n = gcur[set * NB + b] - base;
    int* gp = gpacked + (size_t)set * PADE + base;

    for (int k = tid; k < n; k += 256) {
        int p = gp[k];
        win[k] = p;
        atomicAdd(&hist[(p >> 17) & 127], 1);
    }
    __syncthreads();

    if (tid < 64) {
        int v0 = hist[tid], v1 = hist[64 + tid];
        int i0 = v0;
        #pragma unroll
        for (int off = 1; off < 64; off <<= 1) {
            int u = __shfl_up(i0, off);
            if (tid >= off) i0 += u;
        }
        int t0 = __shfl(i0, 63);
        int i1 = v1;
        #pragma unroll
        for (int off = 1; off < 64; off <<= 1) {
            int u = __shfl_up(i1, off);
            if (tid >= off) i1 += u;
        }
        rst[tid] = i0 - v0;
        rst[64 + tid] = t0 + i1 - v1;
    }
    __syncthreads();

    if (tid < BROWS) {
        int node = b * BROWS + tid;
        if (node < NN) {
            int c = hist[tid];
            float dv = (c > 0) ? (1.0f / sqrtf((float)c)) : 0.0f;
            cnt[set * NN + node] = c;
            dinv[set * NN + node] = dv;
            unsigned bf = (unsigned)(unsigned short)f2bf(dv);
            dsel[set * NN + node] = make_uint2(bf, bf << 16);
            rowstart[set * NN + node] = base + rst[tid];
        }
    }

    for (int k = tid; k < n; k += 256) {
        int p = win[k];
        int d = (p >> 17) & 127;
        int pos = rst[d] + atomicAdd(&lcur[d], 1);
        gp[pos] = p & 0x1FFFF;
    }
}

// ---------------------------------------------------------------------------
// Merged LGConv gather (bf16 rows): one wave per dst node, 8 lanes per edge
// (uint4 = 8 bf16), 2-deep unroll. dot2-bf16 accumulate, f32 accumulators,
// 3-round shfl combine. dsel != null: per-edge bf16-dinv selector (shared
// unscaled input). dsel == null: weight=1 (SQ-chained input). sq: emit
// dinv^2-scaled output so the chained conv runs at weight=1.
// ---------------------------------------------------------------------------
struct GA {
    const unsigned short* x;
    unsigned short* y;
    const int* csr;
    const int* row;
    const int* cnt;
    const float* dinv;
    const uint2* dsel;    // per-src dot2 selector pair, or nullptr for weight=1
    int sq;
};

__global__ __launch_bounds__(256) void k_gather3(GA g0, GA g1, GA g2, int perset) {
    const int bset = blockIdx.x / perset;
    const int blk = blockIdx.x - bset * perset;
    const GA ga = (bset == 0) ? g0 : (bset == 1) ? g1 : g2;
    const int node = blk * 4 + (threadIdx.x >> 6);
    const int lane = threadIdx.x & 63;
    const int slot = lane >> 3, fo = lane & 7;
    const int n = ga.cnt[node];
    float acc[8] = {0.f, 0.f, 0.f, 0.f, 0.f, 0.f, 0.f, 0.f};

    if (n > 0) {
        const int* lst = ga.csr + ga.row[node];
        if (ga.dsel == nullptr) {
            const unsigned sl = SEL_LO, sh = SEL_HI;
            int i = slot;
            for (; i + 8 < n; i += 16) {
                int s0 = lst[i], s1 = lst[i + 8];
                uint4 v0 = *(const uint4*)(ga.x + (size_t)s0 * 64 + fo * 8);
                uint4 v1 = *(const uint4*)(ga.x + (size_t)s1 * 64 + fo * 8);
                dotacc(acc, v0, sl, sh);
                dotacc(acc, v1, sl, sh);
            }
            if (i < n) {
                int s = lst[i];
                uint4 v = *(const uint4*)(ga.x + (size_t)s * 64 + fo * 8);
                dotacc(acc, v, sl, sh);
            }
        } else {
            const uint2* ds = ga.dsel;
            int i = slot;
            for (; i + 8 < n; i += 16) {
                int s0 = lst[i], s1 = lst[i + 8];
                uint2 w0 = ds[s0], w1 = ds[s1];
                uint4 v0 = *(const uint4*)(ga.x + (size_t)s0 * 64 + fo * 8);
                uint4 v1 = *(const uint4*)(ga.x + (size_t)s1 * 64 + fo * 8);
                dotacc(acc, v0, w0.x, w0.y);
                dotacc(acc, v1, w1.x, w1.y);
            }
            if (i < n) {
                int s = lst[i];
                uint2 w = ds[s];
                uint4 v = *(const uint4*)(ga.x + (size_t)s * 64 + fo * 8);
                dotacc(acc, v, w.x, w.y);
            }
        }
    }

    #pragma unroll
    for (int off = 8; off < 64; off <<= 1) {
        #pragma unroll
        for (int j = 0; j < 8; ++j) acc[j] += __shfl_xor(acc[j], off);
    }
    if (slot == 0) {
        float dn = ga.dinv[node];
        float sc = ga.sq ? dn * dn : dn;
        uint4 r;
        r.x = packbf(sc * acc[0], sc * acc[1]);
        r.y = packbf(sc * acc[2], sc * acc[3]);
        r.z = packbf(sc * acc[4], sc * acc[5]);
        r.w = packbf(sc * acc[6], sc * acc[7]);
        *(uint4*)(ga.y + (size_t)node * 64 + fo * 8) = r;
    }
}

// ---------------------------------------------------------------------------
// Fused tail, MFMA version, bf16 inputs. 64 nodes/block, 4 waves.
// Phase 1: normalize (8-lane slots) -> bf16 Xn[64][200] LDS + 1/norms.
// Phase 2: H=relu(Xn@W1+b1) via 16x16x32 bf16 MFMA, logits, softmax -> attw.
// Phase 3: out = sum_q attw_q * raw_q (bf16 re-read, f32 out).
// ---------------------------------------------------------------------------
__global__ __launch_bounds__(256) void k_final(const unsigned short* __restrict__ xt,
                                               const unsigned short* __restrict__ xy,
                                               const unsigned short* __restrict__ xc,
                                               const short* __restrict__ W1t,
                                               const float* __restrict__ b1,
                                               const float* __restrict__ W2,
                                               const float* __restrict__ b2,
                                               float* __restrict__ out) {
    __shared__ alignas(16) short Xn[64 * XROW];   // 25600 B
    __shared__ float rnorm[3 * 64];
    __shared__ float attw[64][4];
    const int tid = threadIdx.x;
    const int wid = tid >> 6, lane = tid & 63;
    const int slot = lane >> 3, fo = lane & 7;
    const int m0 = wid * 16;
    const int nbase = blockIdx.x * 64;

    // ---- phase 1: 48 rows per wave (16 nodes x 3 branches), 8-lane slots
    #pragma unroll
    for (int it = 0; it < 6; ++it) {
        int idx = it * 8 + slot;              // 0..47 = branch*16 + noff
        int br = idx >> 4, noff = idx & 15;
        int m = m0 + noff;
        int nodeg = nbase + m;
        const unsigned short* xp = (br == 0) ? xt : (br == 1) ? xy : xc;
        float f[8] = {0.f, 0.f, 0.f, 0.f, 0.f, 0.f, 0.f, 0.f};
        if (nodeg < NN) {
            uint4 v = *(const uint4*)(xp + (size_t)nodeg * 64 + fo * 8);
            f[0] = bflo(v.x); f[1] = bfhi(v.x); f[2] = bflo(v.y); f[3] = bfhi(v.y);
            f[4] = bflo(v.z); f[5] = bfhi(v.z); f[6] = bflo(v.w); f[7] = bfhi(v.w);
        }
        float ss = 0.f;
        #pragma unroll
        for (int j = 0; j < 8; ++j) ss = fmaf(f[j], f[j], ss);
        #pragma unroll
        for (int off = 1; off < 8; off <<= 1) ss += __shfl_xor(ss, off);
        float rn = 1.0f / fmaxf(sqrtf(ss), 1e-12f);
        uint4 r;
        r.x = packbf(f[0] * rn, f[1] * rn);
        r.y = packbf(f[2] * rn, f[3] * rn);
        r.z = packbf(f[4] * rn, f[5] * rn);
        r.w = packbf(f[6] * rn, f[7] * rn);
        *(uint4*)&Xn[m * XROW + br * 64 + fo * 8] = r;
        if (fo == 0) rnorm[br * 64 + m] = rn;
    }
    __syncthreads();

    // ---- phase 2: MFMA GEMM + logits + softmax
    const int mrow = lane & 15, g = lane >> 4;
    bf16x8 afr[6];
    #pragma unroll
    for (int kk = 0; kk < 6; ++kk)
        afr[kk] = *(const bf16x8*)&Xn[(m0 + mrow) * XROW + kk * 32 + g * 8];
    f32x4 acc[8];
    #pragma unroll
    for (int nt = 0; nt < 8; ++nt) acc[nt] = (f32x4){0.f, 0.f, 0.f, 0.f};
    #pragma unroll
    for (int nt = 0; nt < 8; ++nt) {
        const short* wp = W1t + (nt * 16 + mrow) * 192 + g * 8;
        #pragma unroll
        for (int kk = 0; kk < 6; ++kk)
            acc[nt] = __builtin_amdgcn_mfma_f32_16x16x32_bf16(
                afr[kk], *(const bf16x8*)(wp + kk * 32), acc[nt], 0, 0, 0);
    }
    float p[4][3] = {};
    #pragma unroll
    for (int nt = 0; nt < 8; ++nt) {
        int col = nt * 16 + mrow;
        float b1v = b1[col];
        float w20 = W2[col * 3 + 0], w21 = W2[col * 3 + 1], w22 = W2[col * 3 + 2];
        #pragma unroll
        for (int i = 0; i < 4; ++i) {
            float h = fmaxf(acc[nt][i] + b1v, 0.f);
            p[i][0] = fmaf(h, w20, p[i][0]);
            p[i][1] = fmaf(h, w21, p[i][1]);
            p[i][2] = fmaf(h, w22, p[i][2]);
        }
    }
    #pragma unroll
    for (int i = 0; i < 4; ++i)
        #pragma unroll
        for (int off = 8; off > 0; off >>= 1) {
            p[i][0] += __shfl_xor(p[i][0], off);
            p[i][1] += __shfl_xor(p[i][1], off);
            p[i][2] += __shfl_xor(p[i][2], off);
        }
    if (mrow == 0) {
        #pragma unroll
        for (int i = 0; i < 4; ++i) {
            int m = m0 + g * 4 + i;
            float l0 = p[i][0] + b2[0], l1 = p[i][1] + b2[1], l2 = p[i][2] + b2[2];
            float mx = fmaxf(l0, fmaxf(l1, l2));
            float e0 = __expf(l0 - mx), e1 = __expf(l1 - mx), e2 = __expf(l2 - mx);
            float inv = 1.0f / (e0 + e1 + e2);
            attw[m][0] = e0 * inv * rnorm[m];
            attw[m][1] = e1 * inv * rnorm[64 + m];
            attw[m][2] = e2 * inv * rnorm[128 + m];
        }
    }
    __syncthreads();

    // ---- phase 3: weighted sum of raw bf16 rows, f32 coalesced out
    #pragma unroll
    for (int it = 0; it < 2; ++it) {
        int m = m0 + it * 8 + slot;
        int nodeg = nbase + m;
        if (nodeg < NN) {
            size_t base = (size_t)nodeg * 64 + fo * 8;
            uint4 tv = *(const uint4*)(xt + base);
            uint4 yv = *(const uint4*)(xy + base);
            uint4 cv = *(const uint4*)(xc + base);
            float wt = attw[m][0], wy = attw[m][1], wc = attw[m][2];
            float4 lo4, hi4;
            lo4.x = wt * bflo(tv.x) + wy * bflo(yv.x) + wc * bflo(cv.x);
            lo4.y = wt * bfhi(tv.x) + wy * bfhi(yv.x) + wc * bfhi(cv.x);
            lo4.z = wt * bflo(tv.y) + wy * bflo(yv.y) + wc * bflo(cv.y);
            lo4.w = wt * bfhi(tv.y) + wy * bfhi(yv.y) + wc * bfhi(cv.y);
            hi4.x = wt * bflo(tv.z) + wy * bflo(yv.z) + wc * bflo(cv.z);
            hi4.y = wt * bfhi(tv.z) + wy * bfhi(yv.z) + wc * bfhi(cv.z);
            hi4.z = wt * bflo(tv.w) + wy * bflo(yv.w) + wc * bflo(cv.w);
            hi4.w = wt * bfhi(tv.w) + wy * bfhi(yv.w) + wc * bfhi(cv.w);
            *(float4*)(out + base) = lo4;
            *(float4*)(out + base + 4) = hi4;
        }
    }
}

// ---------------------------------------------------------------------------
extern "C" void kernel_launch(void* const* d_in, const int* in_sizes, int n_in,
                              void* d_out, int out_size, void* d_ws, size_t ws_size,
                              hipStream_t stream) {
    const float* init_feat = (const float*)d_in[0];
    const float* W1 = (const float*)d_in[1];
    const float* b1 = (const float*)d_in[2];
    const float* W2 = (const float*)d_in[3];
    const float* b2 = (const float*)d_in[4];
    const int* ei[3] = {(const int*)d_in[5], (const int*)d_in[6], (const int*)d_in[7]}; // title, year, cat

    // workspace (~89 MB): 5 bf16 feature buffers + CSR structures
    unsigned short* B0 = (unsigned short*)d_ws;         // initb (shared A src) -> C2 (round B out)
    unsigned short* B1 = B0 + (size_t)NN * 64;          // T1 (A out) -> Cfin (round C out)
    unsigned short* B2 = B1 + (size_t)NN * 64;          // C1 (A out)
    unsigned short* B3 = B2 + (size_t)NN * 64;          // Yfin (A out)
    unsigned short* B4 = B3 + (size_t)NN * 64;          // Tfin (B out)
    float* dinvA = (float*)(B4 + (size_t)NN * 64);      // [3*N]
    uint2* dselA = (uint2*)(dinvA + 3 * NN);            // [3*N] packed selectors
    int* cntA = (int*)(dselA + 3 * NN);                 // [3*N]
    int* rowA = cntA + 3 * NN;                          // [3*N]
    int* gpackedA = rowA + 3 * NN;                      // [3*PADE] (CSR in-place)
    short* W1t = (short*)(gpackedA + (size_t)3 * PADE); // [128*192]
    int* gcurA = (int*)(W1t + 128 * 192);               // [3*NB]

    const int TB = 256;
    const int perset = NN / 4;                          // 25000
    const int finalGrid = (NN + 63) / 64;

    k_prep<<<(128 * 192 + TB - 1) / TB, TB, 0, stream>>>(W1, W1t);
    k_ginit<<<(3 * NB + TB - 1) / TB, TB, 0, stream>>>(gcurA);
    k_tobf<<<(NN * 16 + TB - 1) / TB, TB, 0, stream>>>(init_feat, B0);
    k_bscat<<<3 * NCHUNK, TB, 0, stream>>>(ei[0], ei[1], ei[2], gcurA, gpackedA);
    k_bfin<<<3 * NB, TB, 0, stream>>>(gpackedA, gcurA, cntA, dinvA, dselA, rowA);

    #define MKGA(xp, yp, s, DS, SQ) \
        GA{ (xp), (yp), gpackedA + (size_t)(s) * PADE, rowA + (s) * NN, \
            cntA + (s) * NN, dinvA + (s) * NN, (DS), (SQ) }
    // Round A (shared init src, per-edge dinv selectors):
    //   cat1: B0->C1(B2) sq; title1: B0->T1(B1) sq; year: B0->Yfin(B3)
    {
        GA a0 = MKGA(B0, B2, 2, dselA + 2 * NN, 1);
        GA a1 = MKGA(B0, B1, 0, dselA + 0 * NN, 1);
        GA a2 = MKGA(B0, B3, 1, dselA + 1 * NN, 0);
        k_gather3<<<3 * perset, TB, 0, stream>>>(a0, a1, a2, perset);
    }
    // Round B (weight=1): cat2: C1(B2)->C2(B0) sq; title2: T1(B1)->Tfin(B4)
    {
        GA b0 = MKGA(B2, B0, 2, nullptr, 1);
        GA b1g = MKGA(B1, B4, 0, nullptr, 0);
        k_gather3<<<2 * perset, TB, 0, stream>>>(b0, b1g, b1g, perset);
    }
    // Round C (weight=1): cat3: C2(B0)->Cfin(B1)
    {
        GA c0 = MKGA(B0, B1, 2, nullptr, 0);
        k_gather3<<<perset, TB, 0, stream>>>(c0, c0, c0, perset);
    }
    #undef MKGA

    // xt=title(B4), xy=year(B3), xc=cat(B1)
    k_final<<<finalGrid, TB, 0, stream>>>(B4, B3, B1, W1t, b1, W2, b2, (float*)d_out);
}

// Round 12
// 380.591 us; speedup vs baseline: 1.0290x; 1.0290x over previous
//
#include <hip/hip_runtime.h>

// PDA_GNN: 3-branch LightGCN, bf16 feature storage (f32 arithmetic).
// Pre-scaled inputs (all convs weight=1) + v_dot2_f32_bf16 accumulate.
// Padded-bucket CSR build (in-place), merged-round gathers, MFMA fused tail
// (barrier-free: all LDS wave-private). N=100000, E=1250000, D=64.

constexpr int NN = 100000;
constexpr int NE = 1250000;
constexpr int BROWS = 128;                       // dst nodes per bucket
constexpr int NB = (NN + BROWS - 1) / BROWS;     // 782 buckets
constexpr int PADB = 2048;                       // per-bucket capacity (max ~1780)
constexpr int PADE = NB * PADB;                  // padded edges per set
constexpr int CHUNK = 8192;                      // edges per partition block
constexpr int NCHUNK = (NE + CHUNK - 1) / CHUNK; // 153
constexpr int XROW = 200;                        // bf16 per Xn row (192+8 pad)

typedef short bf16x8 __attribute__((ext_vector_type(8)));
typedef float f32x4 __attribute__((ext_vector_type(4)));

__device__ inline short f2bf(float f) {          // f32 -> bf16 RNE
    unsigned u = __builtin_bit_cast(unsigned, f);
    u += 0x7FFFu + ((u >> 16) & 1u);
    return (short)(u >> 16);
}
__device__ inline unsigned packbf(float a, float b) {
    return (unsigned)(unsigned short)f2bf(a) | ((unsigned)(unsigned short)f2bf(b) << 16);
}
__device__ inline float bflo(unsigned q) { return __builtin_bit_cast(float, q << 16); }
__device__ inline float bfhi(unsigned q) { return __builtin_bit_cast(float, q & 0xFFFF0000u); }

// v_dot2_f32_bf16: D = lo(a)*lo(b) + hi(a)*hi(b) + c   (f32 accumulate)
__device__ inline float dot2bf(unsigned a, unsigned b, float c) {
    float d;
    asm("v_dot2_f32_bf16 %0, %1, %2, %3" : "=v"(d) : "v"(a), "v"(b), "v"(c));
    return d;
}
constexpr unsigned SEL_LO = 0x00003F80u;   // bf16 pair (1.0, 0.0)
constexpr unsigned SEL_HI = 0x3F800000u;   // bf16 pair (0.0, 1.0)

__device__ inline void dotacc(float* acc, uint4 v, unsigned sl, unsigned sh) {
    acc[0] = dot2bf(v.x, sl, acc[0]); acc[1] = dot2bf(v.x, sh, acc[1]);
    acc[2] = dot2bf(v.y, sl, acc[2]); acc[3] = dot2bf(v.y, sh, acc[3]);
    acc[4] = dot2bf(v.z, sl, acc[4]); acc[5] = dot2bf(v.z, sh, acc[5]);
    acc[6] = dot2bf(v.w, sl, acc[6]); acc[7] = dot2bf(v.w, sh, acc[7]);
}

// ---------------------------------------------------------------------------
// Merged prep: W1 [192][128] f32 -> W1t [128][192] bf16; gcur init.
// ---------------------------------------------------------------------------
__global__ __launch_bounds__(256) void k_misc(const float* __restrict__ W1, short* __restrict__ W1t,
                                              int* __restrict__ gcur) {
    int idx = blockIdx.x * 256 + threadIdx.x;
    if (idx < 128 * 192) {
        int n = idx & 127, k = idx >> 7;
        W1t[n * 192 + k] = f2bf(W1[k * 128 + n]);
    }
    if (idx < 3 * NB) gcur[idx] = (idx % NB) * PADB;
}

// ---------------------------------------------------------------------------
// Bucket multisplit into padded regions: LDS-stage 8192 edges, LDS histogram,
// one global atomic per (chunk,bucket), write packed (dlow<<17 | src).
// ---------------------------------------------------------------------------
__global__ __launch_bounds__(256) void k_bscat(const int* __restrict__ e0, const int* __restrict__ e1,
                                               const int* __restrict__ e2,
                                               int* __restrict__ gcur, int* __restrict__ gpacked) {
    __shared__ int lpack[CHUNK];
    __shared__ unsigned short lbkt[CHUNK];
    __shared__ int hist[NB];
    __shared__ int lbase[NB];
    __shared__ int lcur[NB];
    const int tid = threadIdx.x;
    const int set = blockIdx.x / NCHUNK;
    const int chunk = blockIdx.x % NCHUNK;
    const int* ei = (set == 0) ? e0 : (set == 1) ? e1 : e2;
    const int ebase = chunk * CHUNK;

    for (int b = tid; b < NB; b += 256) { hist[b] = 0; lcur[b] = 0; }
    __syncthreads();

    #pragma unroll
    for (int j = 0; j < CHUNK / 256; ++j) {
        int k = tid + j * 256;
        int e = ebase + k;
        if (e < NE) {
            int s = ei[e];
            int d = ei[NE + e];
            int b = d >> 7;
            lpack[k] = ((d & 127) << 17) | s;
            lbkt[k] = (unsigned short)b;
            atomicAdd(&hist[b], 1);
        } else {
            lbkt[k] = 0xFFFFu;
        }
    }
    __syncthreads();
    for (int b = tid; b < NB; b += 256) {
        int h = hist[b];
        if (h > 0) lbase[b] = atomicAdd(&gcur[set * NB + b], h);
    }
    __syncthreads();
    int* gp = gpacked + (size_t)set * PADE;
    #pragma unroll
    for (int j = 0; j < CHUNK / 256; ++j) {
        int k = tid + j * 256;
        unsigned short b = lbkt[k];
        if (b != 0xFFFFu) {
            int pos = lbase[b] + atomicAdd(&lcur[b], 1);
            gp[pos] = lpack[k];
        }
    }
}

// ---------------------------------------------------------------------------
// Per-bucket finalize: stage window in LDS -> per-node cnt/dinv/rowstart
// (coalesced) + in-place rewrite of the window as per-row CSR (src only).
// ---------------------------------------------------------------------------
__global__ __launch_bounds__(256) void k_bfin(int* __restrict__ gpacked, const int* __restrict__ gcur,
                                              int* __restrict__ cnt, float* __restrict__ dinv,
                                              int* __restrict__ rowstart) {
    __shared__ int win[PADB];
    __shared__ int hist[BROWS];
    __shared__ int rst[BROWS];    // prefix within bucket (relative)
    __shared__ int lcur[BROWS];
    const int tid = threadIdx.x;
    const int set = blockIdx.x / NB, b = blockIdx.x % NB;
    if (tid < BROWS) { hist[tid] = 0; lcur[tid] = 0; }
    __syncthreads();

    const int base = b * PADB;
    const int n = gcur[set * NB + b] - base;
    int* gp = gpacked + (size_t)set * PADE + base;

    for (int k = tid; k < n; k += 256) {
        int p = gp[k];
        win[k] = p;
        atomicAdd(&hist[(p >> 17) & 127], 1);
    }
    __syncthreads();

    if (tid < 64) {
        int v0 = hist[tid], v1 = hist[64 + tid];
        int i0 = v0;
        #pragma unroll
        for (int off = 1; off < 64; off <<= 1) {
            int u = __shfl_up(i0, off);
            if (tid >= off) i0 += u;
        }
        int t0 = __shfl(i0, 63);
        int i1 = v1;
        #pragma unroll
        for (int off = 1; off < 64; off <<= 1) {
            int u = __shfl_up(i1, off);
            if (tid >= off) i1 += u;
        }
        rst[tid] = i0 - v0;
        rst[64 + tid] = t0 + i1 - v1;
    }
    __syncthreads();

    if (tid < BROWS) {
        int node = b * BROWS + tid;
        if (node < NN) {
            int c = hist[tid];
            cnt[set * NN + node] = c;
            dinv[set * NN + node] = (c > 0) ? (1.0f / sqrtf((float)c)) : 0.0f;
            rowstart[set * NN + node] = base + rst[tid];
        }
    }

    for (int k = tid; k < n; k += 256) {
        int p = win[k];
        int d = (p >> 17) & 127;
        int pos = rst[d] + atomicAdd(&lcur[d], 1);
        gp[pos] = p & 0x1FFFF;
    }
}

// ---------------------------------------------------------------------------
// init f32 -> three bf16 copies scaled by the per-set dinv[node].
// Makes every conv's edge weight exactly 1.0.
// ---------------------------------------------------------------------------
__global__ __launch_bounds__(256) void k_scale3(const float* __restrict__ x, const float* __restrict__ dinv,
                                                unsigned short* __restrict__ ot,
                                                unsigned short* __restrict__ oy,
                                                unsigned short* __restrict__ oc) {
    int i = blockIdx.x * 256 + threadIdx.x;      // one float4 per thread
    if (i < NN * 16) {
        int node = i >> 4;
        float4 v = ((const float4*)x)[i];
        float dt = dinv[node], dy = dinv[NN + node], dc = dinv[2 * NN + node];
        uint2 rt, ry, rc;
        rt.x = packbf(v.x * dt, v.y * dt); rt.y = packbf(v.z * dt, v.w * dt);
        ry.x = packbf(v.x * dy, v.y * dy); ry.y = packbf(v.z * dy, v.w * dy);
        rc.x = packbf(v.x * dc, v.y * dc); rc.y = packbf(v.z * dc, v.w * dc);
        ((uint2*)ot)[i] = rt;
        ((uint2*)oy)[i] = ry;
        ((uint2*)oc)[i] = rc;
    }
}

// ---------------------------------------------------------------------------
// Merged LGConv gather (bf16 rows, weight=1): one wave per dst node, 8 lanes
// per edge (uint4 = 8 bf16), 2-deep unroll. dot2-bf16 accumulate (no unpack),
// f32 accumulators, 3-round shfl combine. sq: emit dinv^2-scaled output so
// the chained conv also runs at weight=1.
// ---------------------------------------------------------------------------
struct GA {
    const unsigned short* x;
    unsigned short* y;
    const int* csr;
    const int* row;
    const int* cnt;
    const float* dinv;
    int sq;
};

__global__ __launch_bounds__(256) void k_gather3(GA g0, GA g1, GA g2, int perset) {
    const int bset = blockIdx.x / perset;
    const int blk = blockIdx.x - bset * perset;
    const GA ga = (bset == 0) ? g0 : (bset == 1) ? g1 : g2;
    const int node = blk * 4 + (threadIdx.x >> 6);
    const int lane = threadIdx.x & 63;
    const int slot = lane >> 3, fo = lane & 7;
    const int n = ga.cnt[node];
    const unsigned sl = SEL_LO, sh = SEL_HI;
    float acc[8] = {0.f, 0.f, 0.f, 0.f, 0.f, 0.f, 0.f, 0.f};

    if (n > 0) {
        const int* lst = ga.csr + ga.row[node];
        int i = slot;
        for (; i + 8 < n; i += 16) {
            int s0 = lst[i], s1 = lst[i + 8];
            uint4 v0 = *(const uint4*)(ga.x + (size_t)s0 * 64 + fo * 8);
            uint4 v1 = *(const uint4*)(ga.x + (size_t)s1 * 64 + fo * 8);
            dotacc(acc, v0, sl, sh);
            dotacc(acc, v1, sl, sh);
        }
        if (i < n) {
            int s = lst[i];
            uint4 v = *(const uint4*)(ga.x + (size_t)s * 64 + fo * 8);
            dotacc(acc, v, sl, sh);
        }
    }

    #pragma unroll
    for (int off = 8; off < 64; off <<= 1) {
        #pragma unroll
        for (int j = 0; j < 8; ++j) acc[j] += __shfl_xor(acc[j], off);
    }
    if (slot == 0) {
        float dn = ga.dinv[node];
        float sc = ga.sq ? dn * dn : dn;
        uint4 r;
        r.x = packbf(sc * acc[0], sc * acc[1]);
        r.y = packbf(sc * acc[2], sc * acc[3]);
        r.z = packbf(sc * acc[4], sc * acc[5]);
        r.w = packbf(sc * acc[6], sc * acc[7]);
        *(uint4*)(ga.y + (size_t)node * 64 + fo * 8) = r;
    }
}

// ---------------------------------------------------------------------------
// Fused tail, MFMA version, bf16 inputs. 64 nodes/block, 4 waves.
// BARRIER-FREE: every LDS region (Xn rows, rnorm slots, attw rows) is
// wave-private (wave w touches only rows m0..m0+15), so no __syncthreads().
// Phase 1: normalize (8-lane slots) -> bf16 Xn[64][200] LDS + 1/norms.
// Phase 2: H=relu(Xn@W1+b1) via 16x16x32 bf16 MFMA, logits, softmax -> attw.
// Phase 3: out = sum_q attw_q * raw_q (bf16 re-read, f32 out).
// ---------------------------------------------------------------------------
__global__ __launch_bounds__(256) void k_final(const unsigned short* __restrict__ xt,
                                               const unsigned short* __restrict__ xy,
                                               const unsigned short* __restrict__ xc,
                                               const short* __restrict__ W1t,
                                               const float* __restrict__ b1,
                                               const float* __restrict__ W2,
                                               const float* __restrict__ b2,
                                               float* __restrict__ out) {
    __shared__ alignas(16) short Xn[64 * XROW];   // 25600 B
    __shared__ float rnorm[3 * 64];
    __shared__ float attw[64][4];
    const int tid = threadIdx.x;
    const int wid = tid >> 6, lane = tid & 63;
    const int slot = lane >> 3, fo = lane & 7;
    const int m0 = wid * 16;
    const int nbase = blockIdx.x * 64;

    // ---- phase 1: 48 rows per wave (16 nodes x 3 branches), 8-lane slots
    #pragma unroll
    for (int it = 0; it < 6; ++it) {
        int idx = it * 8 + slot;              // 0..47 = branch*16 + noff
        int br = idx >> 4, noff = idx & 15;
        int m = m0 + noff;
        int nodeg = nbase + m;
        const unsigned short* xp = (br == 0) ? xt : (br == 1) ? xy : xc;
        float f[8] = {0.f, 0.f, 0.f, 0.f, 0.f, 0.f, 0.f, 0.f};
        if (nodeg < NN) {
            uint4 v = *(const uint4*)(xp + (size_t)nodeg * 64 + fo * 8);
            f[0] = bflo(v.x); f[1] = bfhi(v.x); f[2] = bflo(v.y); f[3] = bfhi(v.y);
            f[4] = bflo(v.z); f[5] = bfhi(v.z); f[6] = bflo(v.w); f[7] = bfhi(v.w);
        }
        float ss = 0.f;
        #pragma unroll
        for (int j = 0; j < 8; ++j) ss = fmaf(f[j], f[j], ss);
        #pragma unroll
        for (int off = 1; off < 8; off <<= 1) ss += __shfl_xor(ss, off);
        float rn = 1.0f / fmaxf(sqrtf(ss), 1e-12f);
        uint4 r;
        r.x = packbf(f[0] * rn, f[1] * rn);
        r.y = packbf(f[2] * rn, f[3] * rn);
        r.z = packbf(f[4] * rn, f[5] * rn);
        r.w = packbf(f[6] * rn, f[7] * rn);
        *(uint4*)&Xn[m * XROW + br * 64 + fo * 8] = r;
        if (fo == 0) rnorm[br * 64 + m] = rn;
    }

    // ---- phase 2: MFMA GEMM + logits + softmax (wave-private rows)
    const int mrow = lane & 15, g = lane >> 4;
    bf16x8 afr[6];
    #pragma unroll
    for (int kk = 0; kk < 6; ++kk)
        afr[kk] = *(const bf16x8*)&Xn[(m0 + mrow) * XROW + kk * 32 + g * 8];
    f32x4 acc[8];
    #pragma unroll
    for (int nt = 0; nt < 8; ++nt) acc[nt] = (f32x4){0.f, 0.f, 0.f, 0.f};
    #pragma unroll
    for (int nt = 0; nt < 8; ++nt) {
        const short* wp = W1t + (nt * 16 + mrow) * 192 + g * 8;
        #pragma unroll
        for (int kk = 0; kk < 6; ++kk)
            acc[nt] = __builtin_amdgcn_mfma_f32_16x16x32_bf16(
                afr[kk], *(const bf16x8*)(wp + kk * 32), acc[nt], 0, 0, 0);
    }
    float p[4][3] = {};
    #pragma unroll
    for (int nt = 0; nt < 8; ++nt) {
        int col = nt * 16 + mrow;
        float b1v = b1[col];
        float w20 = W2[col * 3 + 0], w21 = W2[col * 3 + 1], w22 = W2[col * 3 + 2];
        #pragma unroll
        for (int i = 0; i < 4; ++i) {
            float h = fmaxf(acc[nt][i] + b1v, 0.f);
            p[i][0] = fmaf(h, w20, p[i][0]);
            p[i][1] = fmaf(h, w21, p[i][1]);
            p[i][2] = fmaf(h, w22, p[i][2]);
        }
    }
    #pragma unroll
    for (int i = 0; i < 4; ++i)
        #pragma unroll
        for (int off = 8; off > 0; off >>= 1) {
            p[i][0] += __shfl_xor(p[i][0], off);
            p[i][1] += __shfl_xor(p[i][1], off);
            p[i][2] += __shfl_xor(p[i][2], off);
        }
    if (mrow == 0) {
        #pragma unroll
        for (int i = 0; i < 4; ++i) {
            int m = m0 + g * 4 + i;
            float l0 = p[i][0] + b2[0], l1 = p[i][1] + b2[1], l2 = p[i][2] + b2[2];
            float mx = fmaxf(l0, fmaxf(l1, l2));
            float e0 = __expf(l0 - mx), e1 = __expf(l1 - mx), e2 = __expf(l2 - mx);
            float inv = 1.0f / (e0 + e1 + e2);
            attw[m][0] = e0 * inv * rnorm[m];
            attw[m][1] = e1 * inv * rnorm[64 + m];
            attw[m][2] = e2 * inv * rnorm[128 + m];
        }
    }

    // ---- phase 3: weighted sum of raw bf16 rows, f32 coalesced out
    #pragma unroll
    for (int it = 0; it < 2; ++it) {
        int m = m0 + it * 8 + slot;
        int nodeg = nbase + m;
        if (nodeg < NN) {
            size_t base = (size_t)nodeg * 64 + fo * 8;
            uint4 tv = *(const uint4*)(xt + base);
            uint4 yv = *(const uint4*)(xy + base);
            uint4 cv = *(const uint4*)(xc + base);
            float wt = attw[m][0], wy = attw[m][1], wc = attw[m][2];
            float4 lo4, hi4;
            lo4.x = wt * bflo(tv.x) + wy * bflo(yv.x) + wc * bflo(cv.x);
            lo4.y = wt * bfhi(tv.x) + wy * bfhi(yv.x) + wc * bfhi(cv.x);
            lo4.z = wt * bflo(tv.y) + wy * bflo(yv.y) + wc * bflo(cv.y);
            lo4.w = wt * bfhi(tv.y) + wy * bfhi(yv.y) + wc * bfhi(cv.y);
            hi4.x = wt * bflo(tv.z) + wy * bflo(yv.z) + wc * bflo(cv.z);
            hi4.y = wt * bfhi(tv.z) + wy * bfhi(yv.z) + wc * bfhi(cv.z);
            hi4.z = wt * bflo(tv.w) + wy * bflo(yv.w) + wc * bflo(cv.w);
            hi4.w = wt * bfhi(tv.w) + wy * bfhi(yv.w) + wc * bfhi(cv.w);
            *(float4*)(out + base) = lo4;
            *(float4*)(out + base + 4) = hi4;
        }
    }
}

// ---------------------------------------------------------------------------
extern "C" void kernel_launch(void* const* d_in, const int* in_sizes, int n_in,
                              void* d_out, int out_size, void* d_ws, size_t ws_size,
                              hipStream_t stream) {
    const float* init_feat = (const float*)d_in[0];
    const float* W1 = (const float*)d_in[1];
    const float* b1 = (const float*)d_in[2];
    const float* W2 = (const float*)d_in[3];
    const float* b2 = (const float*)d_in[4];
    const int* ei[3] = {(const int*)d_in[5], (const int*)d_in[6], (const int*)d_in[7]}; // title, year, cat

    // workspace: 6 bf16 feature buffers + CSR structures (~100 MB)
    unsigned short* P0t = (unsigned short*)d_ws;        // scaled title init -> later Tfin
    unsigned short* P0y = P0t + (size_t)NN * 64;        // scaled year init  -> later C2
    unsigned short* P0c = P0y + (size_t)NN * 64;        // scaled cat init   -> later Cfin
    unsigned short* T1  = P0c + (size_t)NN * 64;        // title conv1
    unsigned short* C1  = T1 + (size_t)NN * 64;         // cat conv1
    unsigned short* Yfin = C1 + (size_t)NN * 64;        // year final
    float* dinvA = (float*)(Yfin + (size_t)NN * 64);    // [3*N]
    int* cntA = (int*)(dinvA + 3 * NN);                 // [3*N]
    int* rowA = cntA + 3 * NN;                          // [3*N]
    int* gpackedA = rowA + 3 * NN;                      // [3*PADE] (CSR in-place)
    short* W1t = (short*)(gpackedA + (size_t)3 * PADE); // [128*192]
    int* gcurA = (int*)(W1t + 128 * 192);               // [3*NB]

    const int TB = 256;
    const int perset = NN / 4;                          // 25000
    const int finalGrid = (NN + 63) / 64;

    k_misc<<<(128 * 192 + TB - 1) / TB, TB, 0, stream>>>(W1, W1t, gcurA);
    k_bscat<<<3 * NCHUNK, TB, 0, stream>>>(ei[0], ei[1], ei[2], gcurA, gpackedA);
    k_bfin<<<3 * NB, TB, 0, stream>>>(gpackedA, gcurA, cntA, dinvA, rowA);
    k_scale3<<<(NN * 16 + TB - 1) / TB, TB, 0, stream>>>(init_feat, dinvA, P0t, P0y, P0c);

    #define MKGA(xp, yp, s, SQ) \
        GA{ (xp), (yp), gpackedA + (size_t)(s) * PADE, rowA + (s) * NN, \
            cntA + (s) * NN, dinvA + (s) * NN, (SQ) }
    // Round A: cat1 (P0c->C1), title1 (P0t->T1), year (P0y->Yfin)
    {
        GA a0 = MKGA(P0c, C1, 2, 1);
        GA a1 = MKGA(P0t, T1, 0, 1);
        GA a2 = MKGA(P0y, Yfin, 1, 0);
        k_gather3<<<3 * perset, TB, 0, stream>>>(a0, a1, a2, perset);
    }
    // Round B: cat2 (C1 -> P0y as C2), title2 (T1 -> P0t as Tfin)
    {
        GA b0 = MKGA(C1, P0y, 2, 1);
        GA b1g = MKGA(T1, P0t, 0, 0);
        k_gather3<<<2 * perset, TB, 0, stream>>>(b0, b1g, b1g, perset);
    }
    // Round C: cat3 (P0y -> P0c as Cfin)
    {
        GA c0 = MKGA(P0y, P0c, 2, 0);
        k_gather3<<<perset, TB, 0, stream>>>(c0, c0, c0, perset);
    }
    #undef MKGA

    // xt=title(P0t), xy=year(Yfin), xc=cat(P0c)
    k_final<<<finalGrid, TB, 0, stream>>>(P0t, Yfin, P0c, W1t, b1, W2, b2, (float*)d_out);
}